// Round 18
// baseline (183.474 us; speedup 1.0000x reference)
//
#include <hip/hip_runtime.h>
#include <math.h>

#define Bb 128
#define Tt 1024
#define Ll 96
#define NSEG 16
#define DELTA 16
#define CUT(s) (1 + ((Tt - 1) * (s)) / NSEG)

// per-batch scalars (floats): [0..N) end_sum; [N..2N) junc_sum;
// (ints) [2N..3N) end_dk; [3N..4N) junc_dk; [4N] ps.
// arrival counters: cnt[b] at ws + Bb*WS_STRIDE.
#define WS_STRIDE 80

typedef float v2f __attribute__((ext_vector_type(2)));
typedef float v4f __attribute__((ext_vector_type(4)));
typedef int   v2i __attribute__((ext_vector_type(2)));

// Cross-group (lane ^ 32) sum via v_permlane32_swap (VALU pipe, not LDS).
static __device__ __forceinline__ float xadd32(float p) {
#if __has_builtin(__builtin_amdgcn_permlane32_swap)
    v2i rr = __builtin_amdgcn_permlane32_swap(__float_as_int(p),
                                              __float_as_int(p), false, false);
    return __int_as_float(rr.x) + __int_as_float(rr.y);
#else
    return p + __shfl_xor(p, 32, 64);
#endif
}

// logZ = sum_s [log(end_s) + ln2 DkEnd_s] - sum_{s>=2}[log(junc_s)+ln2 DkJunc_s]
static __device__ void combine_batch(const float* wsb, float* out, int b) {
    const int* wsi = reinterpret_cast<const int*>(wsb);
    const double LN2 = 0.6931471805599453;
    double acc = 0.0;
    #pragma unroll 1
    for (int s = 1; s <= NSEG; ++s) {
        acc += log((double)wsb[s - 1]) + LN2 * (double)wsi[2 * NSEG + s - 1];
        if (s >= 2)
            acc -= log((double)wsb[NSEG + s - 1]) + LN2 * (double)wsi[3 * NSEG + s - 1];
    }
    out[b] = (float)(acc - (double)wsb[4 * NSEG]);
}

// FORWARD-ONLY overlapped chains (R16 scheme). Round-18 = the proven combo:
//  * NSEG=16 (8.5 waves/CU) + x-queue depth 6 (~310ns lookahead > HBM miss
//    latency): R17's depth-3/NSEG-12 cut both and fell latency-bound
//    (VALUBusy 60% -> 28%, per-step 0.052 -> 0.090us). Reverted.
//  * DELTA=16 (R17: absmax 0.0 at 11 junctions; Birkhoff err ~0.33^16~2e-8).
//    Work = 1023 + 15*16 = 1263 steps (0.91x of R16).
//  * last-arrival combine fold (R17: -16us overhead, race-free: publish ->
//    threadfence -> atomicAdd; the (NSEG+1)-th arrival combines; nobody spins).
__global__ __launch_bounds__(64, 1)
void crf_scan_kernel(
    const float* __restrict__ inputs,      // (B, T, L) fp32
    const int*   __restrict__ labels_idx,  // (B, T) int32
    const float* __restrict__ trans,       // (L, L) fp32
    float*       __restrict__ ws,          // scalars + counters
    float*       __restrict__ out)         // (B, 1) fp32
{
    const int cid = blockIdx.x / Bb;       // 0..NSEG-1 chains, NSEG = scores
    const int b   = blockIdx.x % Bb;
    const int i   = threadIdx.x;           // 0..63

    const float* xbase = inputs + (size_t)b * Tt * Ll;
    float* wsb = ws + (size_t)b * WS_STRIDE;
    int*   wsi = reinterpret_cast<int*>(wsb);
    int*   cnt = reinterpret_cast<int*>(ws + (size_t)Bb * WS_STRIDE);

    if (cid == NSEG) {
        // ================= SCORES =================
        float ps = 0.f;
        const int* lb = labels_idx + b * Tt;
        #pragma unroll 4
        for (int t = i; t < Tt; t += 64) {
            int i0 = lb[t];
            ps += xbase[t * Ll + i0];
            if (t < Tt - 1) ps += trans[i0 * Ll + lb[t + 1]];
        }
        #pragma unroll
        for (int off = 32; off; off >>= 1) ps += __shfl_xor(ps, off, 64);
        if (i == 0) {
            wsb[4 * NSEG] = ps;
            __threadfence();
            int old = atomicAdd(&cnt[b], 1);
            if (old == NSEG) { __threadfence(); combine_batch(wsb, out, b); }
        }
        return;
    }

    const int s  = cid + 1;                          // 1..NSEG
    const int lo = CUT(s - 1), hi = CUT(s);          // segment [lo, hi)
    const int w0 = (s == 1) ? 1 : ((lo - DELTA < 1) ? 1 : lo - DELTA);
    const int jt = (s == 1) ? 0 : (lo - 1);          // junction t (0 = never)

    const int g   = i >> 5;            // group: state half [48g, 48g+48)
    const int j   = i & 31;            // slot: owns cols j, j+32, j+64
    const int g48 = g * 48;
    const int cA  = j, cB = j + 32, cC = j + 64;

    __shared__ __align__(16) float buf[Ll];

#define EP24(X) \
    X(0)  X(1)  X(2)  X(3)  X(4)  X(5)  X(6)  X(7)  X(8)  X(9)  X(10) X(11) \
    X(12) X(13) X(14) X(15) X(16) X(17) X(18) X(19) X(20) X(21) X(22) X(23)

#define EDECL(p) v2f EA##p, EB##p, EC##p;
    EP24(EDECL)
#undef EDECL
#define EINIT(p) { \
        int e0 = (g48 + 2*(p)) * Ll, e1 = (g48 + 2*(p) + 1) * Ll; \
        EA##p = (v2f){__expf(trans[e0 + cA]), __expf(trans[e1 + cA])}; \
        EB##p = (v2f){__expf(trans[e0 + cB]), __expf(trans[e1 + cB])}; \
        EC##p = (v2f){__expf(trans[e0 + cC]), __expf(trans[e1 + cC])}; \
        asm volatile("" ::: "memory"); }
    EP24(EINIT)
#undef EINIT

#define CHUNK(q, p0, p1) { \
        aA0 += (v2f){P##q.x, P##q.y} * EA##p0; \
        aA1 += (v2f){P##q.z, P##q.w} * EA##p1; \
        aB0 += (v2f){P##q.x, P##q.y} * EB##p0; \
        aB1 += (v2f){P##q.z, P##q.w} * EB##p1; \
        aC0 += (v2f){P##q.x, P##q.y} * EC##p0; \
        aC1 += (v2f){P##q.z, P##q.w} * EC##p1; }

#define MATVEC \
        CHUNK(0, 0, 1)   CHUNK(1, 2, 3)   CHUNK(2, 4, 5)   CHUNK(3, 6, 7)   \
        CHUNK(4, 8, 9)   CHUNK(5, 10,11)  CHUNK(6, 12,13)  CHUNK(7, 14,15)  \
        CHUNK(8, 16,17)  CHUNK(9, 18,19)  CHUNK(10,20,21)  CHUNK(11,22,23)

#define PRELOAD { const v4f* qb_ = reinterpret_cast<const v4f*>(buf) + g * 12; \
        P0 = qb_[0]; P1 = qb_[1]; P2  = qb_[2];  P3  = qb_[3];  \
        P4 = qb_[4]; P5 = qb_[5]; P6  = qb_[6];  P7  = qb_[7];  \
        P8 = qb_[8]; P9 = qb_[9]; P10 = qb_[10]; P11 = qb_[11]; \
        Pk = buf[0]; }

    v4f P0,P1,P2,P3,P4,P5,P6,P7,P8,P9,P10,P11;
    float Pk;

    // init at t0 = w0-1: q = exp(x_{t0}) (exact for s=1; warmup seed s>1)
    float qA = __expf(xbase[(w0 - 1) * Ll + cA]);
    float qB = __expf(xbase[(w0 - 1) * Ll + cB]);
    float qC = __expf(xbase[(w0 - 1) * Ll + cC]);
    if (i < 32) { buf[cA] = qA; buf[cB] = qB; buf[cC] = qC; }
    asm volatile("" ::: "memory");
    PRELOAD

    // x queue depth 6: ew = exp(x_t); x2..x7 = rows t+1..t+6
    float ewA = __expf(xbase[w0 * Ll + cA]);
    float ewB = __expf(xbase[w0 * Ll + cB]);
    float ewC = __expf(xbase[w0 * Ll + cC]);
#define ROWF(d) ((w0 + (d) > Tt - 1) ? (Tt - 1) : (w0 + (d)))
    float x2A = xbase[ROWF(1)*Ll+cA], x2B = xbase[ROWF(1)*Ll+cB], x2C = xbase[ROWF(1)*Ll+cC];
    float x3A = xbase[ROWF(2)*Ll+cA], x3B = xbase[ROWF(2)*Ll+cB], x3C = xbase[ROWF(2)*Ll+cC];
    float x4A = xbase[ROWF(3)*Ll+cA], x4B = xbase[ROWF(3)*Ll+cB], x4C = xbase[ROWF(3)*Ll+cC];
    float x5A = xbase[ROWF(4)*Ll+cA], x5B = xbase[ROWF(4)*Ll+cB], x5C = xbase[ROWF(4)*Ll+cC];
    float x6A = xbase[ROWF(5)*Ll+cA], x6B = xbase[ROWF(5)*Ll+cB], x6C = xbase[ROWF(5)*Ll+cC];
    float x7A = xbase[ROWF(6)*Ll+cA], x7B = xbase[ROWF(6)*Ll+cB], x7C = xbase[ROWF(6)*Ll+cC];
#undef ROWF

    int Dk = 0;
    float jsum = 1.f; int jdk = 0;      // junction capture
    #pragma unroll 1
    for (int t = w0; t < hi; ++t) {
        int k = ((__float_as_int(Pk) >> 23) & 0xff) - 127;  // wave-uniform
        Dk += k;
        float r = __uint_as_float((unsigned)(127 - k) << 23); // exact 2^-k
        float wA = ewA * r, wB = ewB * r, wC = ewC * r;

        v2f aA0 = {0.f,0.f}, aA1 = {0.f,0.f};
        v2f aB0 = {0.f,0.f}, aB1 = {0.f,0.f};
        v2f aC0 = {0.f,0.f}, aC1 = {0.f,0.f};
        MATVEC
        v2f tA = aA0 + aA1, tB = aB0 + aB1, tC = aC0 + aC1;
        qA = xadd32(tA.x + tA.y) * wA;
        qB = xadd32(tB.x + tB.y) * wB;
        qC = xadd32(tC.x + tC.y) * wC;

        if (i < 32) { buf[cA] = qA; buf[cB] = qB; buf[cC] = qC; }
        asm volatile("" ::: "memory");
        PRELOAD

        // junction capture (wave-uniform branch; taken once per chain)
        if (t == jt) {
            float ssum = qA + qB + qC;
            #pragma unroll
            for (int off = 16; off; off >>= 1) ssum += __shfl_xor(ssum, off, 64);
            jsum = ssum; jdk = Dk;
        }

        // off-path bookkeeping (overlaps the read-train latency)
        ewA = __expf(x2A); ewB = __expf(x2B); ewC = __expf(x2C);
        x2A = x3A; x2B = x3B; x2C = x3C;
        x3A = x4A; x3B = x4B; x3C = x4C;
        x4A = x5A; x4B = x5B; x4C = x5C;
        x5A = x6A; x5B = x6B; x5C = x6C;
        x6A = x7A; x6B = x7B; x6C = x7C;
        int row = t + 7; if (row > Tt - 1) row = Tt - 1;
        x7A = xbase[row*Ll+cA]; x7B = xbase[row*Ll+cB]; x7C = xbase[row*Ll+cC];
    }

    // end capture at t = hi-1
    float esum = qA + qB + qC;
    #pragma unroll
    for (int off = 16; off; off >>= 1) esum += __shfl_xor(esum, off, 64);

    if (i == 0) {
        wsb[s - 1]            = esum;
        wsb[NSEG + s - 1]     = jsum;
        wsi[2 * NSEG + s - 1] = Dk;
        wsi[3 * NSEG + s - 1] = jdk;
        __threadfence();
        int old = atomicAdd(&cnt[b], 1);
        if (old == NSEG) {   // all NSEG chains + scores have arrived
            __threadfence();
            combine_batch(wsb, out, b);
        }
    }
#undef PRELOAD
#undef MATVEC
#undef CHUNK
#undef EP24
}

extern "C" void kernel_launch(void* const* d_in, const int* in_sizes, int n_in,
                              void* d_out, int out_size, void* d_ws, size_t ws_size,
                              hipStream_t stream) {
    const float* inputs     = (const float*)d_in[0];
    const int*   labels_idx = (const int*)d_in[1];
    const float* trans      = (const float*)d_in[2];
    float*       out        = (float*)d_out;
    float*       ws         = (float*)d_ws;

    // zero only the per-batch arrival counters (512 B)
    hipMemsetAsync((char*)d_ws + (size_t)Bb * WS_STRIDE * sizeof(float), 0,
                   Bb * sizeof(int), stream);
    crf_scan_kernel<<<dim3((NSEG + 1) * Bb), dim3(64), 0, stream>>>(
        inputs, labels_idx, trans, ws, out);
}

// Round 19
// 140.955 us; speedup vs baseline: 1.3016x; 1.3016x over previous
//
#include <hip/hip_runtime.h>
#include <math.h>

#define Bb 128
#define Tt 1024
#define Ll 96
#define NSEG 16
#define DELTA 16
#define CUT(s) (1 + ((Tt - 1) * (s)) / NSEG)

// ws per batch: [0..N) end_sum (f32); [N..2N) junc_sum; [2N..3N) end_dk (i32);
// [3N..4N) junc_dk; [4N] ps.
#define WS_STRIDE 80

typedef float v2f __attribute__((ext_vector_type(2)));
typedef float v4f __attribute__((ext_vector_type(4)));
typedef int   v2i __attribute__((ext_vector_type(2)));

// Cross-group (lane ^ 32) sum via v_permlane32_swap (VALU pipe, not LDS).
static __device__ __forceinline__ float xadd32(float p) {
#if __has_builtin(__builtin_amdgcn_permlane32_swap)
    v2i rr = __builtin_amdgcn_permlane32_swap(__float_as_int(p),
                                              __float_as_int(p), false, false);
    return __int_as_float(rr.x) + __int_as_float(rr.y);
#else
    return p + __shfl_xor(p, 32, 64);
#endif
}

// FORWARD-ONLY overlapped chains (R16 scheme, verbatim structure).
// Round-19 = controlled A/B: EXACT R16 two-kernel layout (no combine fold,
// no atomics, no memset) with the single change DELTA 24->16 (work
// 1383->1263; DELTA=16 validated exact by R17/R18 absmax=0.0).
// Rationale: R17+R18 both contained the in-kernel last-arrival combine and
// both ran at ~0.09-0.10us/step vs R14/15/16's ~0.050-0.052; R18 controlled
// NSEG/depth, leaving the fold as the only common unique feature. This round
// isolates it (alternative: cross-acquisition chip-state variance).
//   logZ telescope: chain s warms up DELTA steps before its segment from
//   y=exp(x_{w0-1}); Birkhoff contraction aligns direction; scale errors
//   telescope via scalars captured at junction (t=lo-1) and end (t=hi-1):
//   logZ = sum_s [log(end_s) + ln2 DkEnd_s]
//        - sum_{s>=2} [log(junc_s) + ln2 DkJunc_s]
__global__ __launch_bounds__(64, 1)
void crf_scan_kernel(
    const float* __restrict__ inputs,      // (B, T, L) fp32
    const int*   __restrict__ labels_idx,  // (B, T) int32
    const float* __restrict__ trans,       // (L, L) fp32
    float*       __restrict__ ws)          // 128 x WS_STRIDE floats
{
    const int cid = blockIdx.x / Bb;       // 0..NSEG-1 chains, NSEG = scores
    const int b   = blockIdx.x % Bb;
    const int i   = threadIdx.x;           // 0..63

    const float* xbase = inputs + (size_t)b * Tt * Ll;
    float* wsb = ws + (size_t)b * WS_STRIDE;
    int*   wsi = reinterpret_cast<int*>(wsb);

    if (cid == NSEG) {
        // ================= SCORES =================
        float ps = 0.f;
        const int* lb = labels_idx + b * Tt;
        #pragma unroll 4
        for (int t = i; t < Tt; t += 64) {
            int i0 = lb[t];
            ps += xbase[t * Ll + i0];
            if (t < Tt - 1) ps += trans[i0 * Ll + lb[t + 1]];
        }
        #pragma unroll
        for (int off = 32; off; off >>= 1) ps += __shfl_xor(ps, off, 64);
        if (i == 0) wsb[4 * NSEG] = ps;
        return;
    }

    const int s  = cid + 1;                          // 1..NSEG
    const int lo = CUT(s - 1), hi = CUT(s);          // segment [lo, hi)
    const int w0 = (s == 1) ? 1 : ((lo - DELTA < 1) ? 1 : lo - DELTA);
    const int jt = (s == 1) ? 0 : (lo - 1);          // junction t (0 = never)

    const int g   = i >> 5;            // group: state half [48g, 48g+48)
    const int j   = i & 31;            // slot: owns cols j, j+32, j+64
    const int g48 = g * 48;
    const int cA  = j, cB = j + 32, cC = j + 64;

    __shared__ __align__(16) float buf[Ll];

#define EP24(X) \
    X(0)  X(1)  X(2)  X(3)  X(4)  X(5)  X(6)  X(7)  X(8)  X(9)  X(10) X(11) \
    X(12) X(13) X(14) X(15) X(16) X(17) X(18) X(19) X(20) X(21) X(22) X(23)

#define EDECL(p) v2f EA##p, EB##p, EC##p;
    EP24(EDECL)
#undef EDECL
    // fwd layout: EA_p = {E[2p'][cA], E[2p'+1][cA]} for own-half elems
#define EINIT(p) { \
        int e0 = (g48 + 2*(p)) * Ll, e1 = (g48 + 2*(p) + 1) * Ll; \
        EA##p = (v2f){__expf(trans[e0 + cA]), __expf(trans[e1 + cA])}; \
        EB##p = (v2f){__expf(trans[e0 + cB]), __expf(trans[e1 + cB])}; \
        EC##p = (v2f){__expf(trans[e0 + cC]), __expf(trans[e1 + cC])}; \
        asm volatile("" ::: "memory"); }
    EP24(EINIT)
#undef EINIT

#define CHUNK(q, p0, p1) { \
        aA0 += (v2f){P##q.x, P##q.y} * EA##p0; \
        aA1 += (v2f){P##q.z, P##q.w} * EA##p1; \
        aB0 += (v2f){P##q.x, P##q.y} * EB##p0; \
        aB1 += (v2f){P##q.z, P##q.w} * EB##p1; \
        aC0 += (v2f){P##q.x, P##q.y} * EC##p0; \
        aC1 += (v2f){P##q.z, P##q.w} * EC##p1; }

#define MATVEC \
        CHUNK(0, 0, 1)   CHUNK(1, 2, 3)   CHUNK(2, 4, 5)   CHUNK(3, 6, 7)   \
        CHUNK(4, 8, 9)   CHUNK(5, 10,11)  CHUNK(6, 12,13)  CHUNK(7, 14,15)  \
        CHUNK(8, 16,17)  CHUNK(9, 18,19)  CHUNK(10,20,21)  CHUNK(11,22,23)

#define PRELOAD { const v4f* qb_ = reinterpret_cast<const v4f*>(buf) + g * 12; \
        P0 = qb_[0]; P1 = qb_[1]; P2  = qb_[2];  P3  = qb_[3];  \
        P4 = qb_[4]; P5 = qb_[5]; P6  = qb_[6];  P7  = qb_[7];  \
        P8 = qb_[8]; P9 = qb_[9]; P10 = qb_[10]; P11 = qb_[11]; \
        Pk = buf[0]; }

    v4f P0,P1,P2,P3,P4,P5,P6,P7,P8,P9,P10,P11;
    float Pk;

    // init state at t0 = w0-1: q = exp(x_{t0}) (exact for s=1; warmup seed)
    float qA = __expf(xbase[(w0 - 1) * Ll + cA]);
    float qB = __expf(xbase[(w0 - 1) * Ll + cB]);
    float qC = __expf(xbase[(w0 - 1) * Ll + cC]);
    if (i < 32) { buf[cA] = qA; buf[cB] = qB; buf[cC] = qC; }
    asm volatile("" ::: "memory");
    PRELOAD

    float ewA = __expf(xbase[w0 * Ll + cA]);
    float ewB = __expf(xbase[w0 * Ll + cB]);
    float ewC = __expf(xbase[w0 * Ll + cC]);
#define ROWF(d) ((w0 + (d) > Tt - 1) ? (Tt - 1) : (w0 + (d)))
    float x2A = xbase[ROWF(1)*Ll+cA], x2B = xbase[ROWF(1)*Ll+cB], x2C = xbase[ROWF(1)*Ll+cC];
    float x3A = xbase[ROWF(2)*Ll+cA], x3B = xbase[ROWF(2)*Ll+cB], x3C = xbase[ROWF(2)*Ll+cC];
    float x4A = xbase[ROWF(3)*Ll+cA], x4B = xbase[ROWF(3)*Ll+cB], x4C = xbase[ROWF(3)*Ll+cC];
    float x5A = xbase[ROWF(4)*Ll+cA], x5B = xbase[ROWF(4)*Ll+cB], x5C = xbase[ROWF(4)*Ll+cC];
    float x6A = xbase[ROWF(5)*Ll+cA], x6B = xbase[ROWF(5)*Ll+cB], x6C = xbase[ROWF(5)*Ll+cC];
    float x7A = xbase[ROWF(6)*Ll+cA], x7B = xbase[ROWF(6)*Ll+cB], x7C = xbase[ROWF(6)*Ll+cC];
#undef ROWF

    int Dk = 0;
    float jsum = 1.f; int jdk = 0;      // junction capture
    #pragma unroll 1
    for (int t = w0; t < hi; ++t) {
        int k = ((__float_as_int(Pk) >> 23) & 0xff) - 127;  // wave-uniform
        Dk += k;
        float r = __uint_as_float((unsigned)(127 - k) << 23); // exact 2^-k
        float wA = ewA * r, wB = ewB * r, wC = ewC * r;

        v2f aA0 = {0.f,0.f}, aA1 = {0.f,0.f};
        v2f aB0 = {0.f,0.f}, aB1 = {0.f,0.f};
        v2f aC0 = {0.f,0.f}, aC1 = {0.f,0.f};
        MATVEC
        v2f tA = aA0 + aA1, tB = aB0 + aB1, tC = aC0 + aC1;
        qA = xadd32(tA.x + tA.y) * wA;
        qB = xadd32(tB.x + tB.y) * wB;
        qC = xadd32(tC.x + tC.y) * wC;

        if (i < 32) { buf[cA] = qA; buf[cB] = qB; buf[cC] = qC; }
        asm volatile("" ::: "memory");
        PRELOAD

        // junction capture (wave-uniform branch; taken once per chain)
        if (t == jt) {
            float ssum = qA + qB + qC;
            #pragma unroll
            for (int off = 16; off; off >>= 1) ssum += __shfl_xor(ssum, off, 64);
            jsum = ssum; jdk = Dk;
        }

        // off-path bookkeeping (overlaps the read-train latency)
        ewA = __expf(x2A); ewB = __expf(x2B); ewC = __expf(x2C);
        x2A = x3A; x2B = x3B; x2C = x3C;
        x3A = x4A; x3B = x4B; x3C = x4C;
        x4A = x5A; x4B = x5B; x4C = x5C;
        x5A = x6A; x5B = x6B; x5C = x6C;
        x6A = x7A; x6B = x7B; x6C = x7C;
        int row = t + 7; if (row > Tt - 1) row = Tt - 1;
        x7A = xbase[row*Ll+cA]; x7B = xbase[row*Ll+cB]; x7C = xbase[row*Ll+cC];
    }

    // end capture at t = hi-1
    float esum = qA + qB + qC;
    #pragma unroll
    for (int off = 16; off; off >>= 1) esum += __shfl_xor(esum, off, 64);

    if (i == 0) {
        wsb[s - 1]            = esum;
        wsb[NSEG + s - 1]     = jsum;
        wsi[2 * NSEG + s - 1] = Dk;
        wsi[3 * NSEG + s - 1] = jdk;
    }
#undef PRELOAD
#undef MATVEC
#undef CHUNK
#undef EP24
}

// logZ = sum_s [log(end_s) + ln2 DkEnd_s] - sum_{s>=2} [log(junc_s) + ln2 DkJunc_s]
__global__ __launch_bounds__(64, 1) void crf_combine_kernel(
    const float* __restrict__ ws, float* __restrict__ out)
{
    const int b = blockIdx.x;
    if (threadIdx.x != 0) return;
    const float* wsb = ws + (size_t)b * WS_STRIDE;
    const int*   wsi = reinterpret_cast<const int*>(wsb);
    const double LN2 = 0.6931471805599453;

    double acc = 0.0;
    #pragma unroll 1
    for (int s = 1; s <= NSEG; ++s) {
        acc += log((double)wsb[s - 1]) + LN2 * (double)wsi[2 * NSEG + s - 1];
        if (s >= 2)
            acc -= log((double)wsb[NSEG + s - 1]) + LN2 * (double)wsi[3 * NSEG + s - 1];
    }
    out[b] = (float)(acc - (double)wsb[4 * NSEG]);
}

extern "C" void kernel_launch(void* const* d_in, const int* in_sizes, int n_in,
                              void* d_out, int out_size, void* d_ws, size_t ws_size,
                              hipStream_t stream) {
    const float* inputs     = (const float*)d_in[0];
    const int*   labels_idx = (const int*)d_in[1];
    const float* trans      = (const float*)d_in[2];
    float*       out        = (float*)d_out;
    float*       ws         = (float*)d_ws;

    crf_scan_kernel<<<dim3((NSEG + 1) * Bb), dim3(64), 0, stream>>>(
        inputs, labels_idx, trans, ws);
    crf_combine_kernel<<<dim3(Bb), dim3(64), 0, stream>>>(ws, out);
}